// Round 18
// baseline (115.478 us; speedup 1.0000x reference)
//
#include <hip/hip_runtime.h>
#include <hip/hip_bf16.h>
#include <math.h>
#include <stdint.h>

#define N_TOKENS 16384
#define DIM 4096
#define NEXP 64

typedef const __attribute__((address_space(1))) void gvoid_t;
typedef __attribute__((address_space(3))) void svoid_t;
typedef short bf16x8 __attribute__((ext_vector_type(8)));
typedef float f32x4 __attribute__((ext_vector_type(4)));

constexpr int TOK_BLK = 16;  // tokens per block -> grid 1024 = 4 blocks/CU

// packed hi/lo split: 8 floats -> bf16x8 hi + bf16x8 lo via v_cvt_pk_bf16_f32
__device__ __forceinline__ void split8(const float4 a, const float4 b,
                                       bf16x8& hi, bf16x8& lo) {
  const float f[8] = {a.x, a.y, a.z, a.w, b.x, b.y, b.z, b.w};
  union { unsigned u[4]; bf16x8 v; } H, L;
#pragma unroll
  for (int p = 0; p < 4; ++p) {
    const float2 fp = make_float2(f[2 * p], f[2 * p + 1]);
    const __hip_bfloat162 hh = __float22bfloat162_rn(fp);
    const unsigned uh = *(const unsigned*)&hh;
    const float h0 = __uint_as_float(uh << 16);
    const float h1 = __uint_as_float(uh & 0xffff0000u);
    const __hip_bfloat162 ll =
        __float22bfloat162_rn(make_float2(fp.x - h0, fp.y - h1));
    H.u[p] = uh;
    L.u[p] = *(const unsigned*)&ll;
  }
  hi = H.v;
  lo = L.v;
}

// ------- K1 (fused, MFMA, T3/T4 2-phase, no k0): logits+softmax+top2+hist ------
// R17 flatness (2x occupancy -> 0%) says k1 is supply/overhead-bound, not
// occupancy-bound. This round removes the k0 dispatch: W staged as RAW FP32
// (identical bytes to the hi+lo bf16 pair) and hi/lo-split IN-REGISTER in the
// compute phase (one extra split8 + 2 ds_read_b128/chunk — noise vs the
// 1600cy HBM cadence). Pipeline structure unchanged (verified R16/17):
//   stage(t+1) [5 glds] ; s_waitcnt vmcnt(5) ; s_barrier ; compute(t) ;
//   s_barrier.  No vmcnt(0) in loop.  LDS exactly 40960 B -> 4 blocks/CU.
// Wave = 16 tokens x 16 experts (nt = wid). MFMA 16x16x32_bf16, m89 layouts
// (R12-17 passed). Both x and W LDS reads use the verified slot^(row&15) key.
__global__ __launch_bounds__(256, 4) void k1_fused(
    const float* __restrict__ x, const float* __restrict__ W,
    float* __restrict__ topw, int* __restrict__ sel, int* __restrict__ cnt) {
  __shared__ __align__(16) unsigned char smem[40960];
  float* const x0 = (float*)smem;                  // 4 KB
  float* const x1 = (float*)(smem + 4096);         // 4 KB
  float* const wf0 = (float*)(smem + 8192);        // 16 KB
  float* const wf1 = (float*)(smem + 24576);       // 16 KB
  float* const lg = (float*)smem;                  // overlay after K-loop
  int* const hist = (int*)(smem + 4608);           // 256 B (within x region)

  const int tid = threadIdx.x;
  const int lane = tid & 63;
  const int wid = __builtin_amdgcn_readfirstlane(tid >> 6);  // wave = N-tile
  const int r = lane & 15;  // A token row / B expert col within tile
  const int g = lane >> 4;  // k-group
  const int tok0 = blockIdx.x * TOK_BLK;

  f32x4 acc = {};  // one 16-expert N-tile

  // stage one 64-k chunk: x 1 glds + W fp32 4 glds = 5 glds/wave
  auto stage = [&](float* xd, float* wfd, int kc) {
    {  // x: 4 rows x 16 slots (1 KB), rows wid*4..+4
      const int r0 = wid * 4;
      const int row = r0 + (lane >> 4);
      const float* src =
          x + (size_t)(tok0 + row) * DIM + kc + 4 * ((lane & 15) ^ (row & 15));
      __builtin_amdgcn_global_load_lds((gvoid_t*)src, (svoid_t*)(xd + r0 * 64),
                                       16, 0, 0);
    }
#pragma unroll
    for (int q = 0; q < 4; ++q) {  // W fp32: 4 rows x 16 slots per glds
      const int r0 = wid * 16 + q * 4;
      const int row = r0 + (lane >> 4);
      const float* src =
          W + (size_t)row * DIM + kc + 4 * ((lane & 15) ^ (row & 15));
      __builtin_amdgcn_global_load_lds((gvoid_t*)src, (svoid_t*)(wfd + r0 * 64),
                                       16, 0, 0);
    }
  };

  auto compute = [&](const float* xb, const float* wfb) {
#pragma unroll
    for (int h = 0; h < 2; ++h) {
      const int s0 = h * 8 + 2 * g;
      const float4 fa = *(const float4*)(xb + r * 64 + 4 * (s0 ^ r));
      const float4 fb = *(const float4*)(xb + r * 64 + 4 * ((s0 + 1) ^ r));
      bf16x8 Ahi, Alo;
      split8(fa, fb, Ahi, Alo);
      const int wrow = wid * 16 + r;
      const float4 wa =
          *(const float4*)(wfb + wrow * 64 + 4 * (s0 ^ (wrow & 15)));
      const float4 wb =
          *(const float4*)(wfb + wrow * 64 + 4 * ((s0 + 1) ^ (wrow & 15)));
      bf16x8 Bhi, Blo;
      split8(wa, wb, Bhi, Blo);
      acc = __builtin_amdgcn_mfma_f32_16x16x32_bf16(Ahi, Bhi, acc, 0, 0, 0);
      acc = __builtin_amdgcn_mfma_f32_16x16x32_bf16(Alo, Bhi, acc, 0, 0, 0);
      acc = __builtin_amdgcn_mfma_f32_16x16x32_bf16(Ahi, Blo, acc, 0, 0, 0);
    }
  };

  stage(x0, wf0, 0);
  for (int t = 0; t < 64; t += 2) {
    // ---- iter t (compute buf0) ----
    if (t + 1 < 64) {
      stage(x1, wf1, (t + 1) * 64);
      asm volatile("s_waitcnt vmcnt(5)" ::: "memory");  // stage(t) landed
    } else {
      asm volatile("s_waitcnt vmcnt(0)" ::: "memory");
    }
    __builtin_amdgcn_sched_barrier(0);
    __builtin_amdgcn_s_barrier();  // all waves' stage(t) visible
    compute(x0, wf0);
    __builtin_amdgcn_s_barrier();  // readers done before buf0 rewrite
    __builtin_amdgcn_sched_barrier(0);
    // ---- iter t+1 (compute buf1) ----
    if (t + 2 < 64) {
      stage(x0, wf0, (t + 2) * 64);
      asm volatile("s_waitcnt vmcnt(5)" ::: "memory");  // stage(t+1) landed
    } else {
      asm volatile("s_waitcnt vmcnt(0)" ::: "memory");
    }
    __builtin_amdgcn_sched_barrier(0);
    __builtin_amdgcn_s_barrier();
    compute(x1, wf1);
    __builtin_amdgcn_s_barrier();
    __builtin_amdgcn_sched_barrier(0);
  }

  // epilogue: publish logits (lg/hist overlay the x staging buffers)
  if (tid < NEXP) hist[tid] = 0;
  // D: token = g*4 + rg, expert = wid*16 + r
#pragma unroll
  for (int rg = 0; rg < 4; ++rg)
    lg[(g * 4 + rg) * 68 + wid * 16 + r] = acc[rg];
  __syncthreads();

  // softmax + top2 per token (threads 0..15), then histogram
  if (tid < TOK_BLK) {
    const float* rowp = lg + tid * 68;
    float4 v[16];
#pragma unroll
    for (int c = 0; c < 16; ++c) v[c] = *(const float4*)(rowp + c * 4);

    float v0 = -INFINITY, v1 = -INFINITY;
    int i0 = 0, i1 = 0;
#define TOP2_STEP(val, idx)                                  \
  {                                                          \
    const float vv = (val);                                  \
    const int ee = (idx);                                    \
    if (vv > v0) { v1 = v0; i1 = i0; v0 = vv; i0 = ee; }     \
    else if (vv > v1) { v1 = vv; i1 = ee; }                  \
  }
#pragma unroll
    for (int c = 0; c < 16; ++c) {
      TOP2_STEP(v[c].x, c * 4 + 0);
      TOP2_STEP(v[c].y, c * 4 + 1);
      TOP2_STEP(v[c].z, c * 4 + 2);
      TOP2_STEP(v[c].w, c * 4 + 3);
    }
#undef TOP2_STEP

    float denom = 0.f;
#pragma unroll
    for (int c = 0; c < 16; ++c) {
      denom += expf(v[c].x - v0);
      denom += expf(v[c].y - v0);
      denom += expf(v[c].z - v0);
      denom += expf(v[c].w - v0);
    }
    const float w0s = 1.0f / denom;  // expf(0)==1 exactly
    const float w1s = expf(v1 - v0) / denom;

    const int tk = tok0 + tid;
    topw[2 * tk + 0] = w0s;
    topw[2 * tk + 1] = w1s;
    sel[2 * tk + 0] = i0;
    sel[2 * tk + 1] = i1;
    atomicAdd(&hist[i0], 1);
    atomicAdd(&hist[i1], 1);
  }
  __syncthreads();
  if (tid < NEXP) {
    const int h = hist[tid];
    if (h) atomicAdd(&cnt[tid * 128 + (blockIdx.x >> 3)], h);  // cnt[e][chunk]
  }
}

// ------ K4 (merged scan+scatter): stable counting-sort permutation + counts ----
__global__ __launch_bounds__(256) void k4_scatter(const int* __restrict__ cnt,
                                                  const int* __restrict__ sel,
                                                  float* __restrict__ gout,
                                                  float* __restrict__ counts_out) {
  __shared__ int tot[NEXP], parts[NEXP], cbs[NEXP], wcnt[4 * NEXP];
  const int tid = threadIdx.x;
  const int b = blockIdx.x;
  const int s = b * 256 + tid;
  const int e = sel[s];
  const int lane = tid & 63;
  const int wv = tid >> 6;
  wcnt[tid] = 0;

  if (tid < NEXP) {
    const int4* row4 = (const int4*)(cnt + tid * 128);
    int run = 0, part = 0;
#pragma unroll
    for (int q = 0; q < 32; ++q) {
      const int4 v = row4[q];
      if (4 * q + 0 < b) part += v.x;
      if (4 * q + 1 < b) part += v.y;
      if (4 * q + 2 < b) part += v.z;
      if (4 * q + 3 < b) part += v.w;
      run += v.x + v.y + v.z + v.w;
    }
    tot[tid] = run;
    parts[tid] = part;
    if (b == 0) counts_out[tid] = (float)run;
  }
  __syncthreads();
  if (tid < NEXP) {
    int g2 = 0;
    for (int q = 0; q < tid; ++q) g2 += tot[q];
    cbs[tid] = g2 + parts[tid];
  }

  unsigned long long mask = ~0ull;
#pragma unroll
  for (int bb = 0; bb < 6; ++bb) {
    const unsigned long long bl = __ballot((e >> bb) & 1);
    mask &= ((e >> bb) & 1) ? bl : ~bl;
  }
  const unsigned long long below = mask & ((1ull << lane) - 1ull);
  const int wr = __popcll(below);
  if (wr == 0) wcnt[wv * NEXP + e] = __popcll(mask);
  __syncthreads();

  int base = cbs[e];
  for (int w2 = 0; w2 < wv; ++w2) base += wcnt[w2 * NEXP + e];
  gout[base + wr] = (float)s;
}

extern "C" void kernel_launch(void* const* d_in, const int* in_sizes, int n_in,
                              void* d_out, int out_size, void* d_ws, size_t ws_size,
                              hipStream_t stream) {
  const float* x = (const float*)d_in[0];
  const float* W = (const float*)d_in[1];
  float* out = (float*)d_out;

  int* sel = (int*)d_ws;       // 128 KB
  int* cnt = sel + N_TOKENS * 2;  // 32 KB (cnt[e][128])

  hipMemsetAsync(cnt, 0, 128 * NEXP * sizeof(int), stream);
  hipLaunchKernelGGL(k1_fused, dim3(N_TOKENS / TOK_BLK), dim3(256), 0, stream,
                     x, W, out, sel, cnt);
  hipLaunchKernelGGL(k4_scatter, dim3((2 * N_TOKENS) / 256), dim3(256), 0, stream,
                     cnt, sel, out + 2 * N_TOKENS,
                     out + 2 * N_TOKENS + 2 * N_TOKENS);
}